// Round 6
// baseline (96.767 us; speedup 1.0000x reference)
//
#include <hip/hip_runtime.h>
#include <math.h>

// Batched dynamic bicycle model, 10 substeps h=0.01f.
// R5 post-mortem: LDS-size change didn't move dur/occupancy -> the phase/
// barrier structure was the limiter, not resources. R6: NO LDS, NO barriers.
// Each thread owns 4 consecutive rows (144B, nine aligned float4 ld/st);
// the AoS->SoA transpose is compile-time register naming. Latency hiding
// purely via TLP + 2 independent packed v2f chains.

typedef float v2f __attribute__((ext_vector_type(2)));
typedef float f4  __attribute__((ext_vector_type(4)));

__device__ __forceinline__ float med3(float x, float lo, float hi) {
    return __builtin_amdgcn_fmed3f(x, lo, hi);
}
__device__ __forceinline__ v2f vfma2(v2f a, v2f b, v2f c) {
    return __builtin_elementwise_fma(a, b, c);
}

__global__ __launch_bounds__(256) void bicycle_kernel(
    const float* __restrict__ state_in,   // (B,9)
    const float* __restrict__ action_in,  // (B,2)
    float* __restrict__ out)              // (B,9)
{
    constexpr float MAX_STEER = (float)(30.0 * 3.141592653589793 / 180.0); // 0.5235988
    constexpr float V_EFF_MIN = (float)(20.0 / 3.6);                       // 5.5555553
    constexpr float FY_F_MAX  = (float)(0.9 * 1500.0 * 9.81 * (1.6 / 2.8)); // 7567.7143
    constexpr float FY_R_MAX  = (float)(0.9 * 1500.0 * 9.81 * (1.2 / 2.8)); // 5675.7857

    const size_t g = (size_t)blockIdx.x * 256 + threadIdx.x;  // 4 rows per thread

    // ---- direct loads: 9 aligned float4 (state) + 2 aligned float4 (action) ----
    const f4* gs = (const f4*)state_in + g * 9;   // g*144 B, 16B-aligned
    f4 s[9];
#pragma unroll
    for (int i = 0; i < 9; ++i) s[i] = gs[i];
    const f4* ga = (const f4*)action_in + g * 2;  // g*32 B
    f4 actA = ga[0], actB = ga[1];

    // ---- compile-time AoS->scalar fan-out (all indices static after unroll) ----
    float S[36];
#pragma unroll
    for (int i = 0; i < 9; ++i) {
        S[4 * i + 0] = s[i].x; S[4 * i + 1] = s[i].y;
        S[4 * i + 2] = s[i].z; S[4 * i + 3] = s[i].w;
    }
    float acts[8] = {actA.x, actA.y, actA.z, actA.w, actB.x, actB.y, actB.z, actB.w};

    v2f x[2], y[2], psi[2], v[2], a[2], delta[2], beta[2], r[2];
    v2f a_ref[2], d_ref[2], cs[2], sn[2];
#pragma unroll
    for (int p = 0; p < 2; ++p) {
        const int ra = (2 * p + 0) * 9;
        const int rb = (2 * p + 1) * 9;
        x[p]     = (v2f){S[ra + 0], S[rb + 0]};
        y[p]     = (v2f){S[ra + 1], S[rb + 1]};
        psi[p]   = (v2f){S[ra + 2], S[rb + 2]};
        v[p]     = (v2f){fmaxf(S[ra + 3], 0.0f), fmaxf(S[rb + 3], 0.0f)};
        a[p]     = (v2f){S[ra + 4], S[rb + 4]};
        delta[p] = (v2f){med3(S[ra + 5], -MAX_STEER, MAX_STEER),
                         med3(S[rb + 5], -MAX_STEER, MAX_STEER)};
        beta[p]  = (v2f){S[ra + 6], S[rb + 6]};
        r[p]     = (v2f){S[ra + 7], S[rb + 7]};
        a_ref[p] = (v2f){med3(acts[4 * p + 0], -6.0f, 3.0f),
                         med3(acts[4 * p + 2], -6.0f, 3.0f)};
        d_ref[p] = (v2f){med3(acts[4 * p + 1], -MAX_STEER, MAX_STEER),
                         med3(acts[4 * p + 3], -MAX_STEER, MAX_STEER)};
        float s0, c0, s1, c1;
        __sincosf(psi[p].x + beta[p].x, &s0, &c0);
        __sincosf(psi[p].y + beta[p].y, &s1, &c1);
        cs[p] = (v2f){c0, c1};
        sn[p] = (v2f){s0, s1};
    }

    // ---- integrate: 10 substeps, 2 independent packed chains ----
#pragma unroll
    for (int k = 0; k < 10; ++k) {
#pragma unroll
        for (int p = 0; p < 2; ++p) {
            v2f v_eff = {fmaxf(v[p].x, V_EFF_MIN), fmaxf(v[p].y, V_EFF_MIN)};
            v2f inv_v = {__builtin_amdgcn_rcpf(v_eff.x), __builtin_amdgcn_rcpf(v_eff.y)};
            v2f t = r[p] * inv_v;
            v2f alpha_f = vfma2((v2f)(1.2f), t, beta[p]) - delta[p];
            v2f alpha_r = vfma2((v2f)(-1.6f), t, beta[p]);
            v2f Ff_raw = alpha_f * -80000.0f;
            v2f Fr_raw = alpha_r * -80000.0f;
            v2f F_yf = {med3(Ff_raw.x, -FY_F_MAX, FY_F_MAX), med3(Ff_raw.y, -FY_F_MAX, FY_F_MAX)};
            v2f F_yr = {med3(Fr_raw.x, -FY_R_MAX, FY_R_MAX), med3(Fr_raw.y, -FY_R_MAX, FY_R_MAX)};
            v2f beta_dot = vfma2(F_yf + F_yr, inv_v * (1.0f / 1500.0f), -r[p]);
            v2f r_dot = vfma2((v2f)(1.2f), F_yf, F_yr * -1.6f) * (1.0f / 2250.0f);

            v2f vh = v[p] * 0.01f;
            x[p] = vfma2(vh, cs[p], x[p]);
            y[p] = vfma2(vh, sn[p], y[p]);

            // incremental heading rotation by d = (r + beta_dot)*h
            v2f d  = (r[p] + beta_dot) * 0.01f;
            v2f cd = vfma2(d * d, (v2f)(-0.5f), (v2f)(1.0f));
            v2f cs_n = vfma2(cs[p], cd, -(sn[p] * d));
            v2f sn_n = vfma2(sn[p], cd, cs[p] * d);

            v2f v_new = vfma2(a[p], (v2f)(0.01f), v[p]);
            v_new = (v2f){fmaxf(v_new.x, 0.0f), fmaxf(v_new.y, 0.0f)};
            psi[p]  = vfma2(r[p], (v2f)(0.01f), psi[p]);
            a[p]    = vfma2(a_ref[p] - a[p], (v2f)(0.1f), a[p]);
            v2f dlt = vfma2(d_ref[p] - delta[p], (v2f)(0.1f), delta[p]);
            delta[p] = (v2f){med3(dlt.x, -MAX_STEER, MAX_STEER), med3(dlt.y, -MAX_STEER, MAX_STEER)};
            beta[p] = vfma2(beta_dot, (v2f)(0.01f), beta[p]);
            r[p]    = vfma2(r_dot, (v2f)(0.01f), r[p]);
            v[p] = v_new;
            cs[p] = cs_n;
            sn[p] = sn_n;
        }
    }

    // ---- compile-time scalar->AoS fan-in, 9 aligned float4 stores ----
#pragma unroll
    for (int p = 0; p < 2; ++p) {
        const int ra = (2 * p + 0) * 9;
        const int rb = (2 * p + 1) * 9;
        S[ra + 0] = x[p].x;     S[rb + 0] = x[p].y;
        S[ra + 1] = y[p].x;     S[rb + 1] = y[p].y;
        S[ra + 2] = psi[p].x;   S[rb + 2] = psi[p].y;
        S[ra + 3] = v[p].x;     S[rb + 3] = v[p].y;
        S[ra + 4] = a[p].x;     S[rb + 4] = a[p].y;
        S[ra + 5] = delta[p].x; S[rb + 5] = delta[p].y;
        S[ra + 6] = beta[p].x;  S[rb + 6] = beta[p].y;
        S[ra + 7] = r[p].x;     S[rb + 7] = r[p].y;
        S[ra + 8] = d_ref[p].x; S[rb + 8] = d_ref[p].y;
    }
    f4* o = (f4*)out + g * 9;
#pragma unroll
    for (int i = 0; i < 9; ++i)
        o[i] = (f4){S[4 * i + 0], S[4 * i + 1], S[4 * i + 2], S[4 * i + 3]};
}

extern "C" void kernel_launch(void* const* d_in, const int* in_sizes, int n_in,
                              void* d_out, int out_size, void* d_ws, size_t ws_size,
                              hipStream_t stream) {
    const float* state  = (const float*)d_in[0];
    const float* action = (const float*)d_in[1];
    float* out = (float*)d_out;
    const int rows = in_sizes[0] / 9;          // 4194304
    const int grid = rows / (4 * 256);         // 4096 blocks, exact
    bicycle_kernel<<<grid, 256, 0, stream>>>(state, action, out);
}

// Round 7
// 57.131 us; speedup vs baseline: 1.6938x; 1.6938x over previous
//
#include <hip/hip_runtime.h>
#include <math.h>

// Batched dynamic bicycle model, 10 substeps h=0.01f.
// R6 post-mortem: direct AoS loads (144B lane stride) = 1.7x regression ->
// coalesced+LDS transpose is mandatory. R7: R5 structure but ZERO barriers:
// wave-private LDS slices (256 rows + 9216B per wave), intra-wave visibility
// via s_waitcnt lgkmcnt(0) only (the single-wave-workgroup mechanism).
// Waves flow through load/transpose/compute/store phases fully decoupled.

typedef float v2f __attribute__((ext_vector_type(2)));
typedef float f4  __attribute__((ext_vector_type(4)));

__device__ __forceinline__ float med3(float x, float lo, float hi) {
    return __builtin_amdgcn_fmed3f(x, lo, hi);
}
__device__ __forceinline__ v2f vfma2(v2f a, v2f b, v2f c) {
    return __builtin_elementwise_fma(a, b, c);
}

__global__ __launch_bounds__(256) void bicycle_kernel(
    const float* __restrict__ state_in,   // (B,9)
    const float* __restrict__ action_in,  // (B,2)
    float* __restrict__ out)              // (B,9)
{
    constexpr float MAX_STEER = (float)(30.0 * 3.141592653589793 / 180.0); // 0.5235988
    constexpr float V_EFF_MIN = (float)(20.0 / 3.6);                       // 5.5555553
    constexpr float FY_F_MAX  = (float)(0.9 * 1500.0 * 9.81 * (1.6 / 2.8)); // 7567.7143
    constexpr float FY_R_MAX  = (float)(0.9 * 1500.0 * 9.81 * (1.2 / 2.8)); // 5675.7857

    __shared__ float smem[4 * 2304];          // 36864 B; 9216 B per wave (private)

    const int tid  = threadIdx.x;
    const int wid  = tid >> 6;
    const int lane = tid & 63;
    const size_t waveRow = (size_t)blockIdx.x * 1024 + (size_t)wid * 256; // 256 rows/wave

    float* ws  = smem + wid * 2304;           // this wave's slice
    f4*    ws4 = (f4*)ws;

    // ---- coalesced loads: 9 float4/lane, wave-contiguous 9216B span ----
    const f4* g4 = (const f4*)(state_in + waveRow * 9);
    f4 rg[9];
#pragma unroll
    for (int i = 0; i < 9; ++i) rg[i] = g4[lane + 64 * i];

    // actions: per-row float2, coalesced (512B/instr per wave)
    const float2* a2 = (const float2*)action_in + waveRow;
    float2 act[4];
#pragma unroll
    for (int j = 0; j < 4; ++j) act[j] = a2[lane + 64 * j];

    // ---- stage state into wave-private LDS (no barrier: wave-sync wait) ----
#pragma unroll
    for (int i = 0; i < 9; ++i) ws4[lane + 64 * i] = rg[i];
    asm volatile("s_waitcnt lgkmcnt(0)" ::: "memory");

    // rows rIdx = lane + 64*(2p+e); stride-9 ds_read -> 2-way bank alias (free)
    v2f x[2], y[2], psi[2], v[2], a[2], delta[2], beta[2], r[2];
    v2f a_ref[2], d_ref[2], cs[2], sn[2];
#pragma unroll
    for (int p = 0; p < 2; ++p) {
        const int r0 = (lane + 64 * (2 * p + 0)) * 9;
        const int r1 = (lane + 64 * (2 * p + 1)) * 9;
        x[p]     = (v2f){ws[r0 + 0], ws[r1 + 0]};
        y[p]     = (v2f){ws[r0 + 1], ws[r1 + 1]};
        psi[p]   = (v2f){ws[r0 + 2], ws[r1 + 2]};
        v[p]     = (v2f){fmaxf(ws[r0 + 3], 0.0f), fmaxf(ws[r1 + 3], 0.0f)};
        a[p]     = (v2f){ws[r0 + 4], ws[r1 + 4]};
        delta[p] = (v2f){med3(ws[r0 + 5], -MAX_STEER, MAX_STEER),
                         med3(ws[r1 + 5], -MAX_STEER, MAX_STEER)};
        beta[p]  = (v2f){ws[r0 + 6], ws[r1 + 6]};
        r[p]     = (v2f){ws[r0 + 7], ws[r1 + 7]};
        a_ref[p] = (v2f){med3(act[2 * p + 0].x, -6.0f, 3.0f),
                         med3(act[2 * p + 1].x, -6.0f, 3.0f)};
        d_ref[p] = (v2f){med3(act[2 * p + 0].y, -MAX_STEER, MAX_STEER),
                         med3(act[2 * p + 1].y, -MAX_STEER, MAX_STEER)};
        float s0, c0, s1, c1;
        __sincosf(psi[p].x + beta[p].x, &s0, &c0);
        __sincosf(psi[p].y + beta[p].y, &s1, &c1);
        cs[p] = (v2f){c0, c1};
        sn[p] = (v2f){s0, s1};
    }

    // ---- integrate: 10 substeps, 2 independent packed chains ----
#pragma unroll
    for (int k = 0; k < 10; ++k) {
#pragma unroll
        for (int p = 0; p < 2; ++p) {
            v2f v_eff = {fmaxf(v[p].x, V_EFF_MIN), fmaxf(v[p].y, V_EFF_MIN)};
            v2f inv_v = {__builtin_amdgcn_rcpf(v_eff.x), __builtin_amdgcn_rcpf(v_eff.y)};
            v2f t = r[p] * inv_v;
            v2f alpha_f = vfma2((v2f)(1.2f), t, beta[p]) - delta[p];
            v2f alpha_r = vfma2((v2f)(-1.6f), t, beta[p]);
            v2f Ff_raw = alpha_f * -80000.0f;
            v2f Fr_raw = alpha_r * -80000.0f;
            v2f F_yf = {med3(Ff_raw.x, -FY_F_MAX, FY_F_MAX), med3(Ff_raw.y, -FY_F_MAX, FY_F_MAX)};
            v2f F_yr = {med3(Fr_raw.x, -FY_R_MAX, FY_R_MAX), med3(Fr_raw.y, -FY_R_MAX, FY_R_MAX)};
            v2f beta_dot = vfma2(F_yf + F_yr, inv_v * (1.0f / 1500.0f), -r[p]);
            v2f r_dot = vfma2((v2f)(1.2f), F_yf, F_yr * -1.6f) * (1.0f / 2250.0f);

            v2f vh = v[p] * 0.01f;
            x[p] = vfma2(vh, cs[p], x[p]);
            y[p] = vfma2(vh, sn[p], y[p]);

            // incremental heading rotation by d = (r + beta_dot)*h
            v2f d  = (r[p] + beta_dot) * 0.01f;
            v2f cd = vfma2(d * d, (v2f)(-0.5f), (v2f)(1.0f));
            v2f cs_n = vfma2(cs[p], cd, -(sn[p] * d));
            v2f sn_n = vfma2(sn[p], cd, cs[p] * d);

            v2f v_new = vfma2(a[p], (v2f)(0.01f), v[p]);
            v_new = (v2f){fmaxf(v_new.x, 0.0f), fmaxf(v_new.y, 0.0f)};
            psi[p]  = vfma2(r[p], (v2f)(0.01f), psi[p]);
            a[p]    = vfma2(a_ref[p] - a[p], (v2f)(0.1f), a[p]);
            v2f dlt = vfma2(d_ref[p] - delta[p], (v2f)(0.1f), delta[p]);
            delta[p] = (v2f){med3(dlt.x, -MAX_STEER, MAX_STEER), med3(dlt.y, -MAX_STEER, MAX_STEER)};
            beta[p] = vfma2(beta_dot, (v2f)(0.01f), beta[p]);
            r[p]    = vfma2(r_dot, (v2f)(0.01f), r[p]);
            v[p] = v_new;
            cs[p] = cs_n;
            sn[p] = sn_n;
        }
    }

    // ---- write rows back to the wave slice (each row touched only by owner) ----
#pragma unroll
    for (int p = 0; p < 2; ++p) {
        const int r0 = (lane + 64 * (2 * p + 0)) * 9;
        const int r1 = (lane + 64 * (2 * p + 1)) * 9;
        ws[r0 + 0] = x[p].x;     ws[r1 + 0] = x[p].y;
        ws[r0 + 1] = y[p].x;     ws[r1 + 1] = y[p].y;
        ws[r0 + 2] = psi[p].x;   ws[r1 + 2] = psi[p].y;
        ws[r0 + 3] = v[p].x;     ws[r1 + 3] = v[p].y;
        ws[r0 + 4] = a[p].x;     ws[r1 + 4] = a[p].y;
        ws[r0 + 5] = delta[p].x; ws[r1 + 5] = delta[p].y;
        ws[r0 + 6] = beta[p].x;  ws[r1 + 6] = beta[p].y;
        ws[r0 + 7] = r[p].x;     ws[r1 + 7] = r[p].y;
        ws[r0 + 8] = d_ref[p].x; ws[r1 + 8] = d_ref[p].y;
    }
    asm volatile("s_waitcnt lgkmcnt(0)" ::: "memory");

    // ---- coalesced nontemporal float4 stores from the wave slice ----
    f4* o4 = (f4*)(out + waveRow * 9);
#pragma unroll
    for (int i = 0; i < 9; ++i)
        __builtin_nontemporal_store(ws4[lane + 64 * i], &o4[lane + 64 * i]);
}

extern "C" void kernel_launch(void* const* d_in, const int* in_sizes, int n_in,
                              void* d_out, int out_size, void* d_ws, size_t ws_size,
                              hipStream_t stream) {
    const float* state  = (const float*)d_in[0];
    const float* action = (const float*)d_in[1];
    float* out = (float*)d_out;
    const int rows = in_sizes[0] / 9;          // 4194304
    const int grid = rows / 1024;              // 4096 blocks, exact
    bicycle_kernel<<<grid, 256, 0, stream>>>(state, action, out);
}

// Round 8
// 56.084 us; speedup vs baseline: 1.7254x; 1.0187x over previous
//
#include <hip/hip_runtime.h>
#include <math.h>

// Batched dynamic bicycle model, 10 substeps h=0.01f.
// R7 post-mortem: barrier removal neutral; limiter is within-wave phase
// serialization (load -> long compute (mem idle) -> store, one shot).
// R8: pipelined persistent waves. Each wave: 4 tiles x 256 rows through its
// private 9216B LDS slice; while computing tile t, loads for t+1 are in
// flight (park regs) and stores of t-1 drain. No barriers; compiler emits
// counted waitcnts (all deps are C-level); DS in-order per wave covers the
// LDS slice reuse.

typedef float v2f __attribute__((ext_vector_type(2)));
typedef float f4  __attribute__((ext_vector_type(4)));

__device__ __forceinline__ float med3(float x, float lo, float hi) {
    return __builtin_amdgcn_fmed3f(x, lo, hi);
}
__device__ __forceinline__ v2f vfma2(v2f a, v2f b, v2f c) {
    return __builtin_elementwise_fma(a, b, c);
}

__global__ __launch_bounds__(256, 4) void bicycle_kernel(
    const float* __restrict__ state_in,   // (B,9)
    const float* __restrict__ action_in,  // (B,2)
    float* __restrict__ out)              // (B,9)
{
    constexpr float MAX_STEER = (float)(30.0 * 3.141592653589793 / 180.0); // 0.5235988
    constexpr float V_EFF_MIN = (float)(20.0 / 3.6);                       // 5.5555553
    constexpr float FY_F_MAX  = (float)(0.9 * 1500.0 * 9.81 * (1.6 / 2.8)); // 7567.7143
    constexpr float FY_R_MAX  = (float)(0.9 * 1500.0 * 9.81 * (1.2 / 2.8)); // 5675.7857

    __shared__ float smem[4 * 2304];          // 9216 B per wave, wave-private

    const int tid  = threadIdx.x;
    const int wid  = tid >> 6;
    const int lane = tid & 63;
    float* ws  = smem + wid * 2304;
    f4*    ws4 = (f4*)ws;

    const size_t W = (size_t)blockIdx.x * 4 + wid;   // global wave id (0..4095)
    // tiles W*4+t (t=0..3), 256 rows each: wave streams 4*9216B contiguous.

    f4     pk[9];    // parked state loads for the NEXT tile (in flight during compute)
    float2 actp[4];  // parked action loads for the NEXT tile

    auto loadp = [&](int t) {                        // issue 13 global loads
        const size_t R = (W * 4 + (size_t)t) * 256;
        const f4* g4 = (const f4*)(state_in + R * 9);
#pragma unroll
        for (int i = 0; i < 9; ++i) pk[i] = g4[lane + 64 * i];
        const float2* a2 = (const float2*)action_in + R;
#pragma unroll
        for (int j = 0; j < 4; ++j) actp[j] = a2[lane + 64 * j];
    };
    auto commit = [&]() {                            // park regs -> LDS slice
#pragma unroll
        for (int i = 0; i < 9; ++i) ws4[lane + 64 * i] = pk[i];
    };

    // ---- prologue: tile 0 into LDS ----
    loadp(0);
    commit();

#pragma unroll
    for (int t = 0; t < 4; ++t) {
        // consume tile-t actions into clamped refs BEFORE reloading actp
        v2f a_ref[2], d_ref[2];
#pragma unroll
        for (int p = 0; p < 2; ++p) {
            a_ref[p] = (v2f){med3(actp[2 * p + 0].x, -6.0f, 3.0f),
                             med3(actp[2 * p + 1].x, -6.0f, 3.0f)};
            d_ref[p] = (v2f){med3(actp[2 * p + 0].y, -MAX_STEER, MAX_STEER),
                             med3(actp[2 * p + 1].y, -MAX_STEER, MAX_STEER)};
        }
        if (t < 3) loadp(t + 1);   // prefetch next tile; latency hides under compute

        // ---- transpose-read tile t rows (stride-9: 2-way bank alias, free) ----
        v2f x[2], y[2], psi[2], v[2], a[2], delta[2], beta[2], r[2], cs[2], sn[2];
#pragma unroll
        for (int p = 0; p < 2; ++p) {
            const int r0 = (lane + 64 * (2 * p + 0)) * 9;
            const int r1 = (lane + 64 * (2 * p + 1)) * 9;
            x[p]     = (v2f){ws[r0 + 0], ws[r1 + 0]};
            y[p]     = (v2f){ws[r0 + 1], ws[r1 + 1]};
            psi[p]   = (v2f){ws[r0 + 2], ws[r1 + 2]};
            v[p]     = (v2f){fmaxf(ws[r0 + 3], 0.0f), fmaxf(ws[r1 + 3], 0.0f)};
            a[p]     = (v2f){ws[r0 + 4], ws[r1 + 4]};
            delta[p] = (v2f){med3(ws[r0 + 5], -MAX_STEER, MAX_STEER),
                             med3(ws[r1 + 5], -MAX_STEER, MAX_STEER)};
            beta[p]  = (v2f){ws[r0 + 6], ws[r1 + 6]};
            r[p]     = (v2f){ws[r0 + 7], ws[r1 + 7]};
            float s0, c0, s1, c1;
            __sincosf(psi[p].x + beta[p].x, &s0, &c0);
            __sincosf(psi[p].y + beta[p].y, &s1, &c1);
            cs[p] = (v2f){c0, c1};
            sn[p] = (v2f){s0, s1};
        }

        // ---- integrate: 10 substeps, 2 independent packed chains ----
#pragma unroll
        for (int k = 0; k < 10; ++k) {
#pragma unroll
            for (int p = 0; p < 2; ++p) {
                v2f v_eff = {fmaxf(v[p].x, V_EFF_MIN), fmaxf(v[p].y, V_EFF_MIN)};
                v2f inv_v = {__builtin_amdgcn_rcpf(v_eff.x), __builtin_amdgcn_rcpf(v_eff.y)};
                v2f tt = r[p] * inv_v;
                v2f alpha_f = vfma2((v2f)(1.2f), tt, beta[p]) - delta[p];
                v2f alpha_r = vfma2((v2f)(-1.6f), tt, beta[p]);
                v2f Ff_raw = alpha_f * -80000.0f;
                v2f Fr_raw = alpha_r * -80000.0f;
                v2f F_yf = {med3(Ff_raw.x, -FY_F_MAX, FY_F_MAX), med3(Ff_raw.y, -FY_F_MAX, FY_F_MAX)};
                v2f F_yr = {med3(Fr_raw.x, -FY_R_MAX, FY_R_MAX), med3(Fr_raw.y, -FY_R_MAX, FY_R_MAX)};
                v2f beta_dot = vfma2(F_yf + F_yr, inv_v * (1.0f / 1500.0f), -r[p]);
                v2f r_dot = vfma2((v2f)(1.2f), F_yf, F_yr * -1.6f) * (1.0f / 2250.0f);

                v2f vh = v[p] * 0.01f;
                x[p] = vfma2(vh, cs[p], x[p]);
                y[p] = vfma2(vh, sn[p], y[p]);

                // incremental heading rotation by d = (r + beta_dot)*h
                v2f d  = (r[p] + beta_dot) * 0.01f;
                v2f cd = vfma2(d * d, (v2f)(-0.5f), (v2f)(1.0f));
                v2f cs_n = vfma2(cs[p], cd, -(sn[p] * d));
                v2f sn_n = vfma2(sn[p], cd, cs[p] * d);

                v2f v_new = vfma2(a[p], (v2f)(0.01f), v[p]);
                v_new = (v2f){fmaxf(v_new.x, 0.0f), fmaxf(v_new.y, 0.0f)};
                psi[p]  = vfma2(r[p], (v2f)(0.01f), psi[p]);
                a[p]    = vfma2(a_ref[p] - a[p], (v2f)(0.1f), a[p]);
                v2f dlt = vfma2(d_ref[p] - delta[p], (v2f)(0.1f), delta[p]);
                delta[p] = (v2f){med3(dlt.x, -MAX_STEER, MAX_STEER), med3(dlt.y, -MAX_STEER, MAX_STEER)};
                beta[p] = vfma2(beta_dot, (v2f)(0.01f), beta[p]);
                r[p]    = vfma2(r_dot, (v2f)(0.01f), r[p]);
                v[p] = v_new;
                cs[p] = cs_n;
                sn[p] = sn_n;
            }
        }

        // ---- writeback rows (DS in-order after the reads above) ----
#pragma unroll
        for (int p = 0; p < 2; ++p) {
            const int r0 = (lane + 64 * (2 * p + 0)) * 9;
            const int r1 = (lane + 64 * (2 * p + 1)) * 9;
            ws[r0 + 0] = x[p].x;     ws[r1 + 0] = x[p].y;
            ws[r0 + 1] = y[p].x;     ws[r1 + 1] = y[p].y;
            ws[r0 + 2] = psi[p].x;   ws[r1 + 2] = psi[p].y;
            ws[r0 + 3] = v[p].x;     ws[r1 + 3] = v[p].y;
            ws[r0 + 4] = a[p].x;     ws[r1 + 4] = a[p].y;
            ws[r0 + 5] = delta[p].x; ws[r1 + 5] = delta[p].y;
            ws[r0 + 6] = beta[p].x;  ws[r1 + 6] = beta[p].y;
            ws[r0 + 7] = r[p].x;     ws[r1 + 7] = r[p].y;
            ws[r0 + 8] = d_ref[p].x; ws[r1 + 8] = d_ref[p].y;
        }

        // ---- readout f4 + coalesced nontemporal stores ----
        f4 st[9];
#pragma unroll
        for (int i = 0; i < 9; ++i) st[i] = ws4[lane + 64 * i];
        const size_t R = (W * 4 + (size_t)t) * 256;
        f4* o4 = (f4*)(out + R * 9);
#pragma unroll
        for (int i = 0; i < 9; ++i)
            __builtin_nontemporal_store(st[i], &o4[lane + 64 * i]);

        // ---- commit parked tile t+1 into the slice (after readout; DS in-order) ----
        if (t < 3) commit();
    }
}

extern "C" void kernel_launch(void* const* d_in, const int* in_sizes, int n_in,
                              void* d_out, int out_size, void* d_ws, size_t ws_size,
                              hipStream_t stream) {
    const float* state  = (const float*)d_in[0];
    const float* action = (const float*)d_in[1];
    float* out = (float*)d_out;
    const int rows = in_sizes[0] / 9;          // 4194304
    // 1024 blocks x 4 waves x 4 tiles x 256 rows = rows, exact; 4 blocks/CU.
    const int grid = rows / 4096;              // 1024
    bicycle_kernel<<<grid, 256, 0, stream>>>(state, action, out);
}

// Round 11
// 55.927 us; speedup vs baseline: 1.7302x; 1.0028x over previous
//
#include <hip/hip_runtime.h>
#include <math.h>

// Batched dynamic bicycle model, 10 substeps h=0.01f.
// R10 post-mortem: compile error — raw_buffer_store_b128 needs
// __amdgpu_buffer_rsrc_t (via __builtin_amdgcn_make_buffer_rsrc), not a
// hand-packed u4 SRD. R11: same kernel with the proper rsrc constructor.
// Streaming stores (aux=19: SC0|NT|SC1, no-allocate) remain TRACKED vmem,
// so compiler waitcnt math stays correct. Closed-form a/delta kept.

typedef float v2f __attribute__((ext_vector_type(2)));
typedef float f4  __attribute__((ext_vector_type(4)));
typedef unsigned int u4 __attribute__((ext_vector_type(4)));

#if __has_builtin(__builtin_amdgcn_make_buffer_rsrc) && __has_builtin(__builtin_amdgcn_raw_buffer_store_b128)
#define USE_BUFFER_STORE 1
#else
#define USE_BUFFER_STORE 0
#endif

__device__ __forceinline__ float med3(float x, float lo, float hi) {
    return __builtin_amdgcn_fmed3f(x, lo, hi);
}
__device__ __forceinline__ v2f vfma2(v2f a, v2f b, v2f c) {
    return __builtin_elementwise_fma(a, b, c);
}
__device__ __forceinline__ v2f vmax2(v2f a, v2f b) {
    return __builtin_elementwise_max(a, b);
}
__device__ __forceinline__ v2f vmin2(v2f a, v2f b) {
    return __builtin_elementwise_min(a, b);
}

__global__ __launch_bounds__(256, 4) void bicycle_kernel(
    const float* __restrict__ state_in,   // (B,9)
    const float* __restrict__ action_in,  // (B,2)
    float* __restrict__ out,              // (B,9)
    unsigned int out_bytes)
{
    constexpr float MAX_STEER = (float)(30.0 * 3.141592653589793 / 180.0); // 0.5235988
    constexpr float V_EFF_MIN = (float)(20.0 / 3.6);                       // 5.5555553
    constexpr float FY_F_MAX  = (float)(0.9 * 1500.0 * 9.81 * (1.6 / 2.8)); // 7567.7143
    constexpr float FY_R_MAX  = (float)(0.9 * 1500.0 * 9.81 * (1.2 / 2.8)); // 5675.7857
    constexpr float CK[11] = {1.0f, 0.9f, 0.81f, 0.729f, 0.6561f, 0.59049f,
                              0.531441f, 0.4782969f, 0.43046721f,
                              0.387420489f, 0.3486784401f};

    __shared__ float smem[4 * 2304];          // 9216 B per wave, wave-private

    const int tid  = threadIdx.x;
    const int wid  = tid >> 6;
    const int lane = tid & 63;
    float* ws  = smem + wid * 2304;
    f4*    ws4 = (f4*)ws;

    const size_t W = (size_t)blockIdx.x * 4 + wid;   // global wave id

#if USE_BUFFER_STORE
    __amdgpu_buffer_rsrc_t srd = __builtin_amdgcn_make_buffer_rsrc(
        (void*)out, /*stride=*/(short)0, /*num_records=*/(int)out_bytes,
        /*flags(word3)=*/0x00020000);
#endif

    f4     pk[9];    // parked state loads for the NEXT tile
    float2 actp[4];  // parked action loads for the NEXT tile

    auto loadp = [&](int t) {
        const size_t R = (W * 4 + (size_t)t) * 256;
        const f4* g4 = (const f4*)(state_in + R * 9);
#pragma unroll
        for (int i = 0; i < 9; ++i) pk[i] = g4[lane + 64 * i];
        const float2* a2 = (const float2*)action_in + R;
#pragma unroll
        for (int j = 0; j < 4; ++j) actp[j] = a2[lane + 64 * j];
    };
    auto commit = [&]() {
#pragma unroll
        for (int i = 0; i < 9; ++i) ws4[lane + 64 * i] = pk[i];
    };

    loadp(0);
    commit();

#pragma unroll
    for (int t = 0; t < 4; ++t) {
        // ---- consume tile-t actions BEFORE actp is overwritten ----
        v2f a_ref[2], d_ref[2];
#pragma unroll
        for (int p = 0; p < 2; ++p) {
            a_ref[p] = (v2f){med3(actp[2 * p + 0].x, -6.0f, 3.0f),
                             med3(actp[2 * p + 1].x, -6.0f, 3.0f)};
            d_ref[p] = (v2f){med3(actp[2 * p + 0].y, -MAX_STEER, MAX_STEER),
                             med3(actp[2 * p + 1].y, -MAX_STEER, MAX_STEER)};
        }

        // ---- transpose-read tile t (stride 9: 2-way bank alias, free) ----
        v2f x[2], y[2], psi[2], v[2], beta[2], r[2], cs[2], sn[2], da[2], dd[2];
#pragma unroll
        for (int p = 0; p < 2; ++p) {
            const int r0 = (lane + 64 * (2 * p + 0)) * 9;
            const int r1 = (lane + 64 * (2 * p + 1)) * 9;
            x[p]     = (v2f){ws[r0 + 0], ws[r1 + 0]};
            y[p]     = (v2f){ws[r0 + 1], ws[r1 + 1]};
            psi[p]   = (v2f){ws[r0 + 2], ws[r1 + 2]};
            v[p]     = vmax2((v2f){ws[r0 + 3], ws[r1 + 3]}, (v2f)(0.0f));
            v2f a0   = (v2f){ws[r0 + 4], ws[r1 + 4]};
            v2f dl0  = (v2f){med3(ws[r0 + 5], -MAX_STEER, MAX_STEER),
                             med3(ws[r1 + 5], -MAX_STEER, MAX_STEER)};
            beta[p]  = (v2f){ws[r0 + 6], ws[r1 + 6]};
            r[p]     = (v2f){ws[r0 + 7], ws[r1 + 7]};
            da[p] = a0  - a_ref[p];        // a_k     = a_ref + 0.9^k * da
            dd[p] = dl0 - d_ref[p];        // delta_k = d_ref + 0.9^k * dd (clamp never binds)
            float s0, c0, s1, c1;
            __sincosf(psi[p].x + beta[p].x, &s0, &c0);
            __sincosf(psi[p].y + beta[p].y, &s1, &c1);
            cs[p] = (v2f){c0, c1};
            sn[p] = (v2f){s0, s1};
        }

        if (t < 3) loadp(t + 1);   // prefetch next tile under this tile's compute

        // ---- integrate: 10 substeps, 2 independent packed chains ----
#pragma unroll
        for (int k = 0; k < 10; ++k) {
#pragma unroll
            for (int p = 0; p < 2; ++p) {
                v2f ak = vfma2((v2f)(CK[k]), da[p], a_ref[p]);
                v2f dk = vfma2((v2f)(CK[k]), dd[p], d_ref[p]);
                v2f v_eff = vmax2(v[p], (v2f)(V_EFF_MIN));
                v2f inv_v = {__builtin_amdgcn_rcpf(v_eff.x), __builtin_amdgcn_rcpf(v_eff.y)};
                v2f tt = r[p] * inv_v;
                v2f alpha_f = vfma2((v2f)(1.2f), tt, beta[p]) - dk;
                v2f alpha_r = vfma2((v2f)(-1.6f), tt, beta[p]);
                v2f F_yf = vmin2(vmax2(alpha_f * -80000.0f, (v2f)(-FY_F_MAX)), (v2f)(FY_F_MAX));
                v2f F_yr = vmin2(vmax2(alpha_r * -80000.0f, (v2f)(-FY_R_MAX)), (v2f)(FY_R_MAX));
                v2f beta_dot = vfma2(F_yf + F_yr, inv_v * (1.0f / 1500.0f), -r[p]);
                v2f r_dot = vfma2((v2f)(1.2f), F_yf, F_yr * -1.6f) * (1.0f / 2250.0f);

                v2f vh = v[p] * 0.01f;
                x[p] = vfma2(vh, cs[p], x[p]);
                y[p] = vfma2(vh, sn[p], y[p]);

                v2f d  = (r[p] + beta_dot) * 0.01f;
                v2f cd = vfma2(d * d, (v2f)(-0.5f), (v2f)(1.0f));
                v2f cs_n = vfma2(cs[p], cd, -(sn[p] * d));
                v2f sn_n = vfma2(sn[p], cd, cs[p] * d);

                v[p]   = vmax2(vfma2(ak, (v2f)(0.01f), v[p]), (v2f)(0.0f));
                psi[p] = vfma2(r[p], (v2f)(0.01f), psi[p]);
                beta[p] = vfma2(beta_dot, (v2f)(0.01f), beta[p]);
                r[p]   = vfma2(r_dot, (v2f)(0.01f), r[p]);
                cs[p] = cs_n;
                sn[p] = sn_n;
            }
        }

        // ---- writeback rows (a_10/delta_10 via closed form) ----
#pragma unroll
        for (int p = 0; p < 2; ++p) {
            v2f a10 = vfma2((v2f)(CK[10]), da[p], a_ref[p]);
            v2f d10 = vfma2((v2f)(CK[10]), dd[p], d_ref[p]);
            const int r0 = (lane + 64 * (2 * p + 0)) * 9;
            const int r1 = (lane + 64 * (2 * p + 1)) * 9;
            ws[r0 + 0] = x[p].x;     ws[r1 + 0] = x[p].y;
            ws[r0 + 1] = y[p].x;     ws[r1 + 1] = y[p].y;
            ws[r0 + 2] = psi[p].x;   ws[r1 + 2] = psi[p].y;
            ws[r0 + 3] = v[p].x;     ws[r1 + 3] = v[p].y;
            ws[r0 + 4] = a10.x;      ws[r1 + 4] = a10.y;
            ws[r0 + 5] = d10.x;      ws[r1 + 5] = d10.y;
            ws[r0 + 6] = beta[p].x;  ws[r1 + 6] = beta[p].y;
            ws[r0 + 7] = r[p].x;     ws[r1 + 7] = r[p].y;
            ws[r0 + 8] = d_ref[p].x; ws[r1 + 8] = d_ref[p].y;
        }

        // ---- readout f4 ----
        f4 st[9];
#pragma unroll
        for (int i = 0; i < 9; ++i) st[i] = ws4[lane + 64 * i];

        // ---- commit parked tile t+1 (all vmem tracked -> waits correct) ----
        if (t < 3) commit();

        // ---- streaming stores: tracked buffer_store with SC0|NT|SC1 ----
        const size_t R = (W * 4 + (size_t)t) * 256;
#if USE_BUFFER_STORE
        const int voff = (int)(R * 36) + lane * 16;   // byte offset, <151MB fits
#pragma unroll
        for (int i = 0; i < 9; ++i)
            __builtin_amdgcn_raw_buffer_store_b128(
                __builtin_bit_cast(u4, st[i]), srd, voff + i * 1024, 0, 19);
#else
        f4* o4 = (f4*)(out + R * 9);
#pragma unroll
        for (int i = 0; i < 9; ++i)
            __builtin_nontemporal_store(st[i], &o4[lane + 64 * i]);
#endif
    }
}

extern "C" void kernel_launch(void* const* d_in, const int* in_sizes, int n_in,
                              void* d_out, int out_size, void* d_ws, size_t ws_size,
                              hipStream_t stream) {
    const float* state  = (const float*)d_in[0];
    const float* action = (const float*)d_in[1];
    float* out = (float*)d_out;
    const int rows = in_sizes[0] / 9;          // 4194304
    const int grid = rows / 4096;              // 1024 blocks; 4 waves x 4 tiles x 256 rows
    bicycle_kernel<<<grid, 256, 0, stream>>>(state, action, out,
                                             (unsigned int)out_size * 4u);
}